// Round 4
// baseline (304.187 us; speedup 1.0000x reference)
//
#include <hip/hip_runtime.h>

#define BATCH 4
#define N_PER 300
#define IN_DIM 256
#define KEY_DIM 32
#define FH 160
#define FW 160
#define HW (FH * FW)                 // 25600
#define NQ (BATCH * N_PER)           // 1200
#define Q_ELEMS (NQ * KEY_DIM)       // 38400 fp32: qry_feats [n][c]
#define KWT_ELEMS (IN_DIM * KEY_DIM) // 8192 fp32: key_w transposed [c][o]
#define PREP_TOTAL (Q_ELEMS + KWT_ELEMS)   // 46592 = 182 * 256 exactly
#define KM_OFF PREP_TOTAL                  // km[b][p][o] starts here
#define KM_ELEMS (BATCH * HW * KEY_DIM)    // 3,276,800 fp32 (13.1 MB)
#define NCH 75                             // queries per seg-block
#define NCHUNKS (N_PER / NCH)              // 4

// ---------------------------------------------------------------------------
// Prep: ws[0..38400) = qry_feats[n][c] = in_feats @ qry_w.T + qry_b
//       ws[38400..46592) = kwT[c][o] = key_w[o][c]
// qry_w staged in LDS transposed (+1 pad) so the c-divergent reads become
// conflict-free LDS broadcasts instead of 32-line global gathers.
// ---------------------------------------------------------------------------
__global__ __launch_bounds__(256) void prep_kernel(
        const float* __restrict__ in_feats,
        const float* __restrict__ qry_w,
        const float* __restrict__ qry_b,
        const float* __restrict__ key_w,
        float* __restrict__ ws) {
    __shared__ float qw[IN_DIM * 33];   // qw[k*33 + o] = qry_w[o][k]
    const int t = threadIdx.x;
    {
        int o = t >> 3;                 // 0..31
        int kbase = (t & 7) * 32;       // 0..224
        const float4* __restrict__ src = (const float4*)(qry_w + o * IN_DIM + kbase);
        #pragma unroll
        for (int j = 0; j < 32; j += 4) {
            float4 v = src[j >> 2];
            qw[(kbase + j + 0) * 33 + o] = v.x;
            qw[(kbase + j + 1) * 33 + o] = v.y;
            qw[(kbase + j + 2) * 33 + o] = v.z;
            qw[(kbase + j + 3) * 33 + o] = v.w;
        }
    }
    __syncthreads();

    int gid = blockIdx.x * 256 + t;
    if (gid < Q_ELEMS) {
        int n = gid >> 5;      // query 0..1199
        int c = gid & 31;      // key-dim channel
        const float4* __restrict__ fr4 = (const float4*)(in_feats + n * IN_DIM);
        float a0 = qry_b[c], a1 = 0.f, a2 = 0.f, a3 = 0.f;
        #pragma unroll 4
        for (int k4 = 0; k4 < IN_DIM / 4; ++k4) {
            float4 f = fr4[k4];
            int k = k4 * 4;
            a0 += f.x * qw[(k + 0) * 33 + c];
            a1 += f.y * qw[(k + 1) * 33 + c];
            a2 += f.z * qw[(k + 2) * 33 + c];
            a3 += f.w * qw[(k + 3) * 33 + c];
        }
        ws[gid] = (a0 + a1) + (a2 + a3);   // ws[n*32 + c]
    } else {
        int i = gid - Q_ELEMS;             // 0..8191
        int c = i >> 5;
        int o = i & 31;
        ws[gid] = key_w[o * IN_DIM + c];   // kwT[c*32 + o]
    }
}

// ---------------------------------------------------------------------------
// keymap: km[b][p][o] = key_b[o] + sum_c kwT[c][o] * feat_map[b,c,p]
// feat reads lane-coalesced, 16 loads in flight; km stored as float4 rows.
// ---------------------------------------------------------------------------
__global__ __launch_bounds__(256) void keymap_kernel(
        const float* __restrict__ feat_map,
        const float* __restrict__ key_b,
        float* __restrict__ ws) {
    const int b = blockIdx.y;
    const int p = blockIdx.x * 256 + threadIdx.x;

    const float* __restrict__ fb  = feat_map + (size_t)b * IN_DIM * HW + p;
    const float* __restrict__ kwT = ws + Q_ELEMS;

    float key[KEY_DIM];
    #pragma unroll
    for (int o = 0; o < KEY_DIM; ++o) key[o] = key_b[o];

    #pragma unroll 16
    for (int c = 0; c < IN_DIM; ++c) {
        float f = fb[(size_t)c * HW];
        const float* __restrict__ kr = kwT + c * KEY_DIM;
        #pragma unroll
        for (int o = 0; o < KEY_DIM; ++o)
            key[o] += kr[o] * f;
    }

    float* __restrict__ kmp = ws + KM_OFF + ((size_t)(b * HW) + p) * KEY_DIM;
    #pragma unroll
    for (int o = 0; o < KEY_DIM; o += 4)
        *(float4*)(kmp + o) = make_float4(key[o], key[o + 1], key[o + 2], key[o + 3]);
}

// ---------------------------------------------------------------------------
// seg: out[b,n,p] = dot32(q[b,n,:], km[b,p,:]) for n in a 75-query chunk.
// grid (100,4,4) = 1600 blocks -> ~25 waves/CU. km row loaded once into
// registers (8x float4, lane-dense); q rows wave-uniform scalar loads.
// ---------------------------------------------------------------------------
__global__ __launch_bounds__(256) void seg_kernel(
        const float* __restrict__ ws,
        float* __restrict__ out) {
    const int b  = blockIdx.y;
    const int p  = blockIdx.x * 256 + threadIdx.x;
    const int n0 = blockIdx.z * NCH;

    const float* __restrict__ kmp = ws + KM_OFF + ((size_t)(b * HW) + p) * KEY_DIM;
    float key[KEY_DIM];
    #pragma unroll
    for (int o = 0; o < KEY_DIM; o += 4) {
        float4 v = *(const float4*)(kmp + o);
        key[o] = v.x; key[o + 1] = v.y; key[o + 2] = v.z; key[o + 3] = v.w;
    }

    const float* __restrict__ qb = ws + ((size_t)b * N_PER + n0) * KEY_DIM;
    float* __restrict__ ob = out + ((size_t)(b * N_PER + n0)) * HW + p;
    #pragma unroll 3
    for (int n = 0; n < NCH; ++n) {
        const float* __restrict__ qn = qb + n * KEY_DIM;
        float a0 = 0.f, a1 = 0.f, a2 = 0.f, a3 = 0.f;
        #pragma unroll
        for (int c = 0; c < KEY_DIM; c += 4) {
            a0 += qn[c + 0] * key[c + 0];
            a1 += qn[c + 1] * key[c + 1];
            a2 += qn[c + 2] * key[c + 2];
            a3 += qn[c + 3] * key[c + 3];
        }
        ob[(size_t)n * HW] = (a0 + a1) + (a2 + a3);
    }
}

extern "C" void kernel_launch(void* const* d_in, const int* in_sizes, int n_in,
                              void* d_out, int out_size, void* d_ws, size_t ws_size,
                              hipStream_t stream) {
    const float* in_feats = (const float*)d_in[0];  // [1200, 256]
    const float* feat_map = (const float*)d_in[1];  // [4, 256, 160, 160]
    const float* qry_w    = (const float*)d_in[2];  // [32, 256]
    const float* qry_b    = (const float*)d_in[3];  // [32]
    const float* key_w    = (const float*)d_in[4];  // [32, 256]
    const float* key_b    = (const float*)d_in[5];  // [32]
    float* ws  = (float*)d_ws;   // needs (46592 + 3276800)*4 B = 13.3 MB
    float* out = (float*)d_out;  // [1200, 160, 160] fp32

    prep_kernel<<<dim3(PREP_TOTAL / 256), dim3(256), 0, stream>>>(
        in_feats, qry_w, qry_b, key_w, ws);

    keymap_kernel<<<dim3(HW / 256, BATCH), dim3(256), 0, stream>>>(
        feat_map, key_b, ws);

    seg_kernel<<<dim3(HW / 256, BATCH, NCHUNKS), dim3(256), 0, stream>>>(ws, out);
}